// Round 4
// baseline (801.165 us; speedup 1.0000x reference)
//
#include <hip/hip_runtime.h>

// DIAGNOSTIC ROUND: R3 gather body executed 6x in one dispatch so the kernel
// displaces the harness's 313-320us fillBuffer dispatches from rocprof's
// top-5 and we finally see FETCH_SIZE / WRITE_SIZE / VALUBusy / Occupancy for
// the gather itself. Passes 0..4 use index shifts (idx + k*166667) mod 1e6
// (still uniform random, no artificial cache warmth) and dead-store to
// distinct 25.6MB d_ws slices (DSE-proof); pass 5 uses the true indices and
// writes d_out -> output stays correct. Per-pass structure is byte-identical
// to R3 (2 rows/thread, 20 gathers in flight, nontemporal stores), so
// dispatch_dur/6 calibrates the true kernel time. Revert to single-pass next
// round.

typedef float v4f __attribute__((ext_vector_type(4)));

constexpr int D      = 128;
constexpr int CHUNKS = D / 4;     // 32 lanes per row (float4 chunks)
constexpr int S      = 10;        // num_sample
constexpr int PASSES = 6;
constexpr unsigned NROWS = 1000000u;

__global__ __launch_bounds__(256, 4)
void mean_agg_diag(const int* __restrict__ idx,
                   const float* __restrict__ feat,
                   float* __restrict__ out,
                   float* __restrict__ ws,
                   int halfB)
{
    const int tid  = blockIdx.x * blockDim.x + threadIdx.x;
    const int c    = tid & 31;
    const int pair = tid >> 5;
    if (pair >= halfB) return;

    const int row0 = pair;
    const int row1 = pair + halfB;

    const int* i0 = idx + (long)row0 * S;
    const int* i1 = idx + (long)row1 * S;

    int r[2 * S];
#pragma unroll
    for (int s = 0; s < S; ++s) { r[s] = i0[s]; r[S + s] = i1[s]; }

    const float* base = feat + c * 4;
    const long rowoff0 = (long)row0 * D + c * 4;
    const long rowoff1 = (long)row1 * D + c * 4;

#pragma unroll 1
    for (int p = 0; p < PASSES; ++p) {
        // passes 0..4: shifted (still uniform) indices; pass 5: true indices
        const unsigned shift = (p == PASSES - 1) ? 0u : (unsigned)(p + 1) * 166667u;

        int rp[2 * S];
#pragma unroll
        for (int s = 0; s < 2 * S; ++s) {
            unsigned t = (unsigned)r[s] + shift;
            rp[s] = (t >= NROWS) ? (int)(t - NROWS) : (int)t;
        }

        v4f v[2 * S];
#pragma unroll
        for (int s = 0; s < 2 * S; ++s) {
            v[s] = *(const v4f*)(base + (long)rp[s] * D);
        }

        v4f a0 = (v4f)(0.f);
        v4f a1 = (v4f)(0.f);
#pragma unroll
        for (int s = 0; s < S; ++s) {
            a0 += v[s];
            a1 += v[S + s];
        }
        a0 *= 0.1f;
        a1 *= 0.1f;

        float* dst = (p == PASSES - 1)
                       ? out
                       : ws + (size_t)p * (size_t)(2 * halfB) * D;  // distinct slices
        __builtin_nontemporal_store(a0, (v4f*)(dst + rowoff0));
        __builtin_nontemporal_store(a1, (v4f*)(dst + rowoff1));
    }
}

extern "C" void kernel_launch(void* const* d_in, const int* in_sizes, int n_in,
                              void* d_out, int out_size, void* d_ws, size_t ws_size,
                              hipStream_t stream) {
    const int*   idx  = (const int*)d_in[0];    // [B, S] int
    const float* feat = (const float*)d_in[1];  // [N, D] fp32
    float*       out  = (float*)d_out;          // [B, D] fp32
    float*       ws   = (float*)d_ws;           // >= 5 * 25.6 MB used

    const int B     = out_size / D;             // 50000
    const int halfB = B / 2;

    const int threads = 256;
    const int total   = halfB * CHUNKS;
    const int blocks  = (total + threads - 1) / threads;

    mean_agg_diag<<<blocks, threads, 0, stream>>>(idx, feat, out, ws, halfB);
}